// Round 3
// baseline (698.006 us; speedup 1.0000x reference)
//
#include <hip/hip_runtime.h>
#include <stdint.h>

// Fused LN1 -> Linear(1024->256) -> LN2, single pass over X.
//   LN1 folded into epilogue: y = rs*(X @ (W*g1)^T - mu*s1) + s2
//   3-MFMA split: Wg = Wh + Wl (bf16), x = xh + xl (bf16):
//     acc += xh*Wh + xl*Wh + xh*Wl      (validated: absmax 0.0156 passed)
//   v3: ZERO LDS / ZERO barriers in K-loop. All operands global->VGPR:
//     W (1 MB) is L2-resident; X A-frags loaded in MFMA layout, hi/lo split
//     + LN1 stats computed in registers. X prefetched 1 iter ahead.
//     Latency-bound fix per round-2 counters (10% HBM, 16% Mfma, all-low).

#define D_MODEL 1024
#define D_PROJ  256
#define BM      64
#define BK      32
#define KITERS  32
#define NTHR    512
#define EPS     1e-5f

typedef __attribute__((ext_vector_type(4))) float  f32x4;
typedef __attribute__((ext_vector_type(8))) __bf16 bf16x8;

// ---------------- prep: Wg = W*g1 -> (Wh, Wl) row-major bf16; s1, s2 ----------------
__global__ __launch_bounds__(256) void prep_kernel(
    const float* __restrict__ W, const float* __restrict__ g1,
    const float* __restrict__ b1, const float* __restrict__ bias,
    __bf16* __restrict__ wh, __bf16* __restrict__ wl,
    float* __restrict__ s1, float* __restrict__ s2) {
  const int p = blockIdx.x;
  const int t = threadIdx.x;                 // owns k = 4t..4t+3
  f32x4 w4  = *(const f32x4*)(W  + (size_t)p * D_MODEL + t * 4);
  f32x4 g4  = *(const f32x4*)(g1 + t * 4);
  f32x4 b14 = *(const f32x4*)(b1 + t * 4);
  union { __bf16 h[4]; uint64_t u; } ph, pl;
  float a = 0.f, c = 0.f;
#pragma unroll
  for (int j = 0; j < 4; ++j) {
    float wg = w4[j] * g4[j];
    a += wg;
    c += b14[j] * w4[j];
    __bf16 hb = (__bf16)wg;
    ph.h[j] = hb;
    pl.h[j] = (__bf16)(wg - (float)hb);
  }
  *(uint64_t*)(wh + (size_t)p * D_MODEL + t * 4) = ph.u;
  *(uint64_t*)(wl + (size_t)p * D_MODEL + t * 4) = pl.u;
#pragma unroll
  for (int m = 1; m < 64; m <<= 1) {
    a += __shfl_xor(a, m, 64);
    c += __shfl_xor(c, m, 64);
  }
  __shared__ float ra[4], rc[4];
  if ((t & 63) == 0) { ra[t >> 6] = a; rc[t >> 6] = c; }
  __syncthreads();
  if (t == 0) {
    s1[p] = ra[0] + ra[1] + ra[2] + ra[3];
    s2[p] = rc[0] + rc[1] + rc[2] + rc[3] + bias[p];
  }
}

// ---------------- fused main ----------------
__global__ __launch_bounds__(NTHR, 3) void fused_kernel(
    const float* __restrict__ X, const __bf16* __restrict__ wh,
    const __bf16* __restrict__ wl, const float* __restrict__ s1,
    const float* __restrict__ s2, const float* __restrict__ g2,
    const float* __restrict__ b2, float* __restrict__ out) {
  __shared__ float mu_s[BM], rs_s[BM];
  __shared__ float red_s[4][BM], red_q[4][BM];

  const int tid  = threadIdx.x;
  const int lane = tid & 63;
  const int wid  = tid >> 6;                  // 0..7
  const int lrow = lane & 15, lgrp = lane >> 4;
  const int wr = wid >> 2, wc = wid & 3;      // wave tile: 32 rows x 64 cols
  const int row0 = blockIdx.x * BM;

  // A-frag row pointers (m=0,1), already offset by this lane's k-slot
  const float* xp0 = X + (size_t)(row0 + wr * 32 + lrow) * D_MODEL + lgrp * 8;
  const float* xp1 = xp0 + (size_t)16 * D_MODEL;
  // B-frag base offsets per n (elements), shared by wh/wl
  // woff(n) = (wc*64 + n*16 + lrow)*D_MODEL + lgrp*8

  f32x4 acc[2][4];
#pragma unroll
  for (int m = 0; m < 2; ++m)
#pragma unroll
    for (int n = 0; n < 4; ++n) acc[m][n] = (f32x4){0.f, 0.f, 0.f, 0.f};
  float ps0 = 0.f, pq0 = 0.f, ps1 = 0.f, pq1 = 0.f;

  // prologue: X chunk 0 into stage A
  f32x4 xA0a = *(const f32x4*)(xp0);
  f32x4 xA0b = *(const f32x4*)(xp0 + 4);
  f32x4 xA1a = *(const f32x4*)(xp1);
  f32x4 xA1b = *(const f32x4*)(xp1 + 4);
  f32x4 xB0a, xB0b, xB1a, xB1b;

#define STEP(IT, C0a, C0b, C1a, C1b, N0a, N0b, N1a, N1b)                          \
  {                                                                               \
    const int itn = ((IT) + 1 < KITERS) ? (IT) + 1 : (IT);                        \
    N0a = *(const f32x4*)(xp0 + itn * BK);                                        \
    N0b = *(const f32x4*)(xp0 + itn * BK + 4);                                    \
    N1a = *(const f32x4*)(xp1 + itn * BK);                                        \
    N1b = *(const f32x4*)(xp1 + itn * BK + 4);                                    \
    /* convert current X + LN1 stats (all in regs) */                             \
    bf16x8 ah0, al0, ah1, al1;                                                    \
    _Pragma("unroll")                                                             \
    for (int j = 0; j < 4; ++j) {                                                 \
      float x = C0a[j];  ps0 += x; pq0 += x * x;                                  \
      __bf16 hb = (__bf16)x; ah0[j] = hb; al0[j] = (__bf16)(x - (float)hb);       \
      float y = C0b[j];  ps0 += y; pq0 += y * y;                                  \
      __bf16 hc = (__bf16)y; ah0[4 + j] = hc; al0[4 + j] = (__bf16)(y - (float)hc);\
      float z = C1a[j];  ps1 += z; pq1 += z * z;                                  \
      __bf16 hd = (__bf16)z; ah1[j] = hd; al1[j] = (__bf16)(z - (float)hd);       \
      float w = C1b[j];  ps1 += w; pq1 += w * w;                                  \
      __bf16 he = (__bf16)w; ah1[4 + j] = he; al1[4 + j] = (__bf16)(w - (float)he);\
    }                                                                             \
    _Pragma("unroll")                                                             \
    for (int n = 0; n < 4; ++n) {                                                 \
      const size_t wo = (size_t)(wc * 64 + n * 16 + lrow) * D_MODEL +             \
                        lgrp * 8 + (IT) * BK;                                     \
      bf16x8 bh = *(const bf16x8*)(wh + wo);                                      \
      bf16x8 bl = *(const bf16x8*)(wl + wo);                                      \
      acc[0][n] = __builtin_amdgcn_mfma_f32_16x16x32_bf16(ah0, bh, acc[0][n], 0, 0, 0); \
      acc[1][n] = __builtin_amdgcn_mfma_f32_16x16x32_bf16(ah1, bh, acc[1][n], 0, 0, 0); \
      acc[0][n] = __builtin_amdgcn_mfma_f32_16x16x32_bf16(al0, bh, acc[0][n], 0, 0, 0); \
      acc[1][n] = __builtin_amdgcn_mfma_f32_16x16x32_bf16(al1, bh, acc[1][n], 0, 0, 0); \
      acc[0][n] = __builtin_amdgcn_mfma_f32_16x16x32_bf16(ah0, bl, acc[0][n], 0, 0, 0); \
      acc[1][n] = __builtin_amdgcn_mfma_f32_16x16x32_bf16(ah1, bl, acc[1][n], 0, 0, 0); \
    }                                                                             \
  }

  for (int it = 0; it < KITERS; it += 2) {
    STEP(it,     xA0a, xA0b, xA1a, xA1b, xB0a, xB0b, xB1a, xB1b);
    STEP(it + 1, xB0a, xB0b, xB1a, xB1b, xA0a, xA0b, xA1a, xA1b);
  }
#undef STEP

  // ---- LN1 stats: reduce across lgrp (lanes ^16, ^32), publish once ----
  ps0 += __shfl_xor(ps0, 16, 64); ps0 += __shfl_xor(ps0, 32, 64);
  pq0 += __shfl_xor(pq0, 16, 64); pq0 += __shfl_xor(pq0, 32, 64);
  ps1 += __shfl_xor(ps1, 16, 64); ps1 += __shfl_xor(ps1, 32, 64);
  pq1 += __shfl_xor(pq1, 16, 64); pq1 += __shfl_xor(pq1, 32, 64);
  if (wc == 0 && lgrp == 0) {
    float mu0 = ps0 * (1.0f / D_MODEL);
    float v0  = pq0 * (1.0f / D_MODEL) - mu0 * mu0;
    mu_s[wr * 32 + lrow] = mu0;
    rs_s[wr * 32 + lrow] = rsqrtf(v0 + EPS);
    float mu1 = ps1 * (1.0f / D_MODEL);
    float v1  = pq1 * (1.0f / D_MODEL) - mu1 * mu1;
    mu_s[wr * 32 + 16 + lrow] = mu1;
    rs_s[wr * 32 + 16 + lrow] = rsqrtf(v1 + EPS);
  }
  __syncthreads();

  // ---- epilogue: LN1 affine correction, LN2 stats, normalize, store ----
  float s1r[4], s2r[4], g2r[4], b2r[4];
#pragma unroll
  for (int n = 0; n < 4; ++n) {
    const int p = wc * 64 + n * 16 + lrow;
    s1r[n] = s1[p]; s2r[n] = s2[p];
    g2r[n] = g2[p]; b2r[n] = b2[p];
  }
#pragma unroll
  for (int m = 0; m < 2; ++m) {
#pragma unroll
    for (int j = 0; j < 4; ++j) {
      const int r = wr * 32 + m * 16 + lgrp * 4 + j;
      float muv = mu_s[r], rsv = rs_s[r];
      float rs_ = 0.f, rq_ = 0.f;
#pragma unroll
      for (int n = 0; n < 4; ++n) {
        float y = rsv * (acc[m][n][j] - muv * s1r[n]) + s2r[n];
        acc[m][n][j] = y;
        rs_ += y; rq_ += y * y;
      }
#pragma unroll
      for (int msk = 1; msk < 16; msk <<= 1) {
        rs_ += __shfl_xor(rs_, msk, 64);
        rq_ += __shfl_xor(rq_, msk, 64);
      }
      if (lrow == 0) { red_s[wc][r] = rs_; red_q[wc][r] = rq_; }
    }
  }
  __syncthreads();
#pragma unroll
  for (int m = 0; m < 2; ++m) {
#pragma unroll
    for (int j = 0; j < 4; ++j) {
      const int r = wr * 32 + m * 16 + lgrp * 4 + j;
      float S = red_s[0][r] + red_s[1][r] + red_s[2][r] + red_s[3][r];
      float Q = red_q[0][r] + red_q[1][r] + red_q[2][r] + red_q[3][r];
      float mu2  = S * (1.0f / D_PROJ);
      float var2 = Q * (1.0f / D_PROJ) - mu2 * mu2;
      float rs2  = rsqrtf(var2 + EPS);
      float* orow = out + (size_t)(row0 + r) * D_PROJ;
#pragma unroll
      for (int n = 0; n < 4; ++n)
        orow[wc * 64 + n * 16 + lrow] = (acc[m][n][j] - mu2) * rs2 * g2r[n] + b2r[n];
    }
  }
}

extern "C" void kernel_launch(void* const* d_in, const int* in_sizes, int n_in,
                              void* d_out, int out_size, void* d_ws, size_t ws_size,
                              hipStream_t stream) {
  const float* X  = (const float*)d_in[0];
  const float* g1 = (const float*)d_in[1];
  const float* b1 = (const float*)d_in[2];
  const float* W  = (const float*)d_in[3];
  const float* bb = (const float*)d_in[4];
  const float* g2 = (const float*)d_in[5];
  const float* b2 = (const float*)d_in[6];
  float* out = (float*)d_out;
  const int n_tok = in_sizes[0] / D_MODEL;

  __bf16* wh = (__bf16*)d_ws;                          // 512 KB row-major bf16 hi
  __bf16* wl = wh + (size_t)D_PROJ * D_MODEL;          // 512 KB row-major bf16 lo
  float*  s1 = (float*)(wl + (size_t)D_PROJ * D_MODEL);
  float*  s2 = s1 + D_PROJ;

  prep_kernel<<<D_PROJ, 256, 0, stream>>>(W, g1, b1, bb, wh, wl, s1, s2);
  fused_kernel<<<n_tok / BM, NTHR, 0, stream>>>(X, wh, wl, s1, s2, g2, b2, out);
}